// Round 3
// baseline (217.479 us; speedup 1.0000x reference)
//
#include <hip/hip_runtime.h>
#include <stdint.h>

#define DEV __device__ __forceinline__

typedef __attribute__((ext_vector_type(8))) unsigned short frag8;    // 8 bf16 = 4 VGPR
typedef __attribute__((ext_vector_type(4))) float f32x4;
typedef __attribute__((ext_vector_type(8))) unsigned short ushort8;
typedef __attribute__((ext_vector_type(4))) unsigned short ushort4v;

DEV unsigned short f2bf(float f) {
  union { float f; unsigned u; } x; x.f = f;
  unsigned r = x.u + 0x7fffu + ((x.u >> 16) & 1u);   // RNE
  return (unsigned short)(r >> 16);
}
DEV float bf2f(unsigned short b) {
  union { unsigned u; float f; } x; x.u = ((unsigned)b) << 16;
  return x.f;
}

DEV void gload_lds16(const void* g, void* l) {
  __builtin_amdgcn_global_load_lds((const __attribute__((address_space(1))) void*)g,
                                   (__attribute__((address_space(3))) void*)l, 16, 0, 0);
}

DEV void mfma_bf16(f32x4& c, frag8 a, frag8 b) {
  asm("v_mfma_f32_16x16x32_bf16 %0, %1, %2, %0" : "+v"(c) : "v"(a), "v"(b));
}

// counted wait: stage-t landed (stage-t+1's 8 loads stay in flight), then sync.
DEV void wait_vm8_barrier() {
  asm volatile("s_waitcnt vmcnt(8)" ::: "memory");
  __builtin_amdgcn_s_barrier();
  __builtin_amdgcn_sched_barrier(0);
}
DEV void wait_vm0_barrier() {
  asm volatile("s_waitcnt vmcnt(0)" ::: "memory");
  __builtin_amdgcn_s_barrier();
  __builtin_amdgcn_sched_barrier(0);
}
// raw barrier WITHOUT vmcnt drain (a __syncthreads here would re-drain the
// in-flight prefetch). ds_reads of COMPUTE are already consumed (lgkm waits
// inserted before the MFMAs that read them).
DEV void raw_barrier() {
  __builtin_amdgcn_s_barrier();
  __builtin_amdgcn_sched_barrier(0);
}

// ---------------------------------------------------------------------------
// C[M,N] = A[M,K]*B[N,K]^T, bf16 in / f32 acc. 128x128 tile, BK=64, 4 waves,
// double-buffered LDS, counted-vmcnt 2-phase prefetch (T4-style: never drain
// in main loop). XOR-swizzled LDS via pre-swizzled global source (rule #21).
// 1D grid + bijective XCD swizzle (T1, m204).
// MODE: 0 = bf16 out
//       1 = f32 out (+bias)
//       2 = fused projections (bz<2 bf16 out; bz==2 transposed into vT)
//       3 = scores: e = exp(s*scale), bf16 out, atomic rowsum accumulation
//       4 = PV: bf16 out, normalized by 1/rowsum[row]
// ---------------------------------------------------------------------------
template<int BIAS, int MODE>
__global__ __launch_bounds__(256)
void gemm_bt(const unsigned short* __restrict__ A,
             const unsigned short* __restrict__ Bm,
             const float* __restrict__ bias0, const float* __restrict__ bias1,
             const float* __restrict__ bias2,
             float* __restrict__ rowsum,
             void* __restrict__ Cv,
             int N, int K, float scale,
             long sA, long sB, long sC,
             int nx, int ny)
{
  __shared__ unsigned short lds[2][2][128 * 64];   // [buf][A/B], 64 KiB

  const int tid  = threadIdx.x;
  const int lane = tid & 63;
  const int wave = tid >> 6;
  const int wm   = wave >> 1;           // 2x2 waves, 64x64 each
  const int wn   = wave & 1;

  // ---- bijective XCD swizzle (m204) + grid decomposition ----
  const unsigned nwg = gridDim.x;
  const unsigned orig = blockIdx.x;
  const unsigned qq = nwg >> 3, rr = nwg & 7;
  const unsigned xcd = orig & 7, jj = orig >> 3;
  const unsigned wg = (xcd < rr ? xcd * (qq + 1) : rr * (qq + 1) + (xcd - rr) * qq) + jj;
  const unsigned bx = wg % (unsigned)nx;
  const unsigned tt = wg / (unsigned)nx;
  const unsigned by = tt % (unsigned)ny;
  const unsigned bz = tt / (unsigned)ny;

  const int bm = (int)by * 128;
  const int bn = (int)bx * 128;

  A  += (size_t)bz * (size_t)sA;
  Bm += (size_t)bz * (size_t)sB;

  // ---- staging addresses (per wave: 4 instrs of 1KB = 8 rows each side) ----
  const int r8  = lane >> 3;
  const int l8  = lane & 7;
  const int swz = ((l8 ^ r8) << 4);     // pre-swizzled global byte column
  const size_t Kb = (size_t)K * 2;

  const char* gA = (const char*)A  + (size_t)(bm + wave * 32 + r8) * Kb + swz;
  const char* gB = (const char*)Bm + (size_t)(bn + wave * 32 + r8) * Kb + swz;
  char* lA0 = (char*)&lds[0][0][0] + wave * 32 * 128;
  char* lB0 = (char*)&lds[0][1][0] + wave * 32 * 128;
  char* lA1 = (char*)&lds[1][0][0] + wave * 32 * 128;
  char* lB1 = (char*)&lds[1][1][0] + wave * 32 * 128;

  // ---- fragment read addresses ----
  const int cr = lane & 15;
  const int kq = lane >> 4;
  const int base16 = ((kq ^ (cr & 7)) << 4);
  const char* rA0 = (const char*)&lds[0][0][0] + (wm * 64 + cr) * 128;
  const char* rB0 = (const char*)&lds[0][1][0] + (wn * 64 + cr) * 128;
  const char* rA1 = (const char*)&lds[1][0][0] + (wm * 64 + cr) * 128;
  const char* rB1 = (const char*)&lds[1][1][0] + (wn * 64 + cr) * 128;

  f32x4 acc[4][4];
  #pragma unroll
  for (int m = 0; m < 4; ++m)
    #pragma unroll
    for (int n = 0; n < 4; ++n)
      acc[m][n] = f32x4{0.f, 0.f, 0.f, 0.f};

  auto STAGE = [&](int t, char* la, char* lb) {
    const char* ga = gA + (size_t)t * 128;
    const char* gb = gB + (size_t)t * 128;
    gload_lds16(ga,               la);
    gload_lds16(gb,               lb);
    gload_lds16(ga +  8 * Kb,     la + 1024);
    gload_lds16(gb +  8 * Kb,     lb + 1024);
    gload_lds16(ga + 16 * Kb,     la + 2048);
    gload_lds16(gb + 16 * Kb,     lb + 2048);
    gload_lds16(ga + 24 * Kb,     la + 3072);
    gload_lds16(gb + 24 * Kb,     lb + 3072);
  };
  auto COMPUTE = [&](const char* ra, const char* rb) {
    #pragma unroll
    for (int kk = 0; kk < 2; ++kk) {
      const int off = base16 ^ (kk << 6);
      frag8 a[4], b[4];
      #pragma unroll
      for (int f = 0; f < 4; ++f) {
        a[f] = *(const frag8*)(ra + f * 2048 + off);
        b[f] = *(const frag8*)(rb + f * 2048 + off);
      }
      #pragma unroll
      for (int m = 0; m < 4; ++m)
        #pragma unroll
        for (int n = 0; n < 4; ++n)
          mfma_bf16(acc[m][n], a[m], b[n]);
    }
  };

  const int nk = K >> 6;
  STAGE(0, lA0, lB0);
  for (int t = 0; t < nk; ++t) {
    const bool odd = t & 1;
    if (t + 1 < nk) {
      STAGE(t + 1, odd ? lA0 : lA1, odd ? lB0 : lB1);
      wait_vm8_barrier();               // stage-t resident; t+1 stays in flight
    } else {
      wait_vm0_barrier();               // tail: drain last stage
    }
    COMPUTE(odd ? rA1 : rA0, odd ? rB1 : rB0);
    raw_barrier();                      // readers done before next overwrite
  }

  // ---- epilogue: C/D layout col=lane&15, row=(lane>>4)*4+i (m89-verified) --
  const float* bias = bias0;
  if constexpr (MODE == 2) bias = (bz == 0) ? bias0 : (bz == 1) ? bias1 : bias2;

  #pragma unroll
  for (int m = 0; m < 4; ++m) {
    const int gr0 = bm + wm * 64 + m * 16 + kq * 4;
    float psum[4] = {0.f, 0.f, 0.f, 0.f};       // MODE 3 row partials
    float inv0 = 1.f, inv1 = 1.f, inv2 = 1.f, inv3 = 1.f;
    if constexpr (MODE == 4) {
      const float4 rs = *(const float4*)&bias0[(size_t)bz * 2048 + gr0];
      inv0 = 1.f / rs.x; inv1 = 1.f / rs.y; inv2 = 1.f / rs.z; inv3 = 1.f / rs.w;
    }
    #pragma unroll
    for (int n = 0; n < 4; ++n) {
      const int gc = bn + wn * 64 + n * 16 + cr;
      float bb = 0.f;
      if constexpr (BIAS) bb = bias[gc];
      float v0 = acc[m][n][0], v1 = acc[m][n][1], v2 = acc[m][n][2], v3 = acc[m][n][3];
      v0 += bb; v1 += bb; v2 += bb; v3 += bb;
      if constexpr (MODE == 1) {
        float* C = (float*)Cv + (size_t)bz * (size_t)sC;
        C[(size_t)(gr0 + 0) * N + gc] = v0;
        C[(size_t)(gr0 + 1) * N + gc] = v1;
        C[(size_t)(gr0 + 2) * N + gc] = v2;
        C[(size_t)(gr0 + 3) * N + gc] = v3;
      } else if constexpr (MODE == 3) {
        // e = exp(s*scale); store bf16; accumulate row partials (use the
        // bf16-rounded value so numerator and denominator match exactly)
        unsigned short* C = (unsigned short*)Cv + (size_t)bz * (size_t)sC;
        unsigned short e0 = f2bf(__expf(v0 * scale));
        unsigned short e1 = f2bf(__expf(v1 * scale));
        unsigned short e2 = f2bf(__expf(v2 * scale));
        unsigned short e3 = f2bf(__expf(v3 * scale));
        C[(size_t)(gr0 + 0) * N + gc] = e0;
        C[(size_t)(gr0 + 1) * N + gc] = e1;
        C[(size_t)(gr0 + 2) * N + gc] = e2;
        C[(size_t)(gr0 + 3) * N + gc] = e3;
        psum[0] += bf2f(e0); psum[1] += bf2f(e1);
        psum[2] += bf2f(e2); psum[3] += bf2f(e3);
      } else if constexpr (MODE == 4) {
        unsigned short* C = (unsigned short*)Cv + (size_t)bz * (size_t)sC;
        C[(size_t)(gr0 + 0) * N + gc] = f2bf(v0 * inv0);
        C[(size_t)(gr0 + 1) * N + gc] = f2bf(v1 * inv1);
        C[(size_t)(gr0 + 2) * N + gc] = f2bf(v2 * inv2);
        C[(size_t)(gr0 + 3) * N + gc] = f2bf(v3 * inv3);
      } else if constexpr (MODE == 2) {
        if (bz == 2) {
          unsigned short* C = (unsigned short*)Cv + (size_t)2 * (size_t)sC;
          ushort4v u;
          u[0] = f2bf(v0); u[1] = f2bf(v1); u[2] = f2bf(v2); u[3] = f2bf(v3);
          *(ushort4v*)&C[((size_t)(gr0 >> 11) << 21) + (size_t)gc * 2048 + (gr0 & 2047)] = u;
        } else {
          unsigned short* C = (unsigned short*)Cv + (size_t)bz * (size_t)sC;
          C[(size_t)(gr0 + 0) * N + gc] = f2bf(v0);
          C[(size_t)(gr0 + 1) * N + gc] = f2bf(v1);
          C[(size_t)(gr0 + 2) * N + gc] = f2bf(v2);
          C[(size_t)(gr0 + 3) * N + gc] = f2bf(v3);
        }
      } else {
        unsigned short* C = (unsigned short*)Cv + (size_t)bz * (size_t)sC;
        C[(size_t)(gr0 + 0) * N + gc] = f2bf(v0);
        C[(size_t)(gr0 + 1) * N + gc] = f2bf(v1);
        C[(size_t)(gr0 + 2) * N + gc] = f2bf(v2);
        C[(size_t)(gr0 + 3) * N + gc] = f2bf(v3);
      }
    }
    if constexpr (MODE == 3) {
      // reduce each row partial over the 16 lanes sharing the row (same kq)
      #pragma unroll
      for (int j = 0; j < 4; ++j) {
        float p = psum[j];
        p += __shfl_xor(p, 1);
        p += __shfl_xor(p, 2);
        p += __shfl_xor(p, 4);
        p += __shfl_xor(p, 8);
        if (cr == 0) atomicAdd(&rowsum[(size_t)bz * 2048 + gr0 + j], p);
      }
    }
  }
}

// ---------------------------------------------------------------------------
// fused f32 -> bf16 for three equal-size tensors (blockIdx.y selects)
// ---------------------------------------------------------------------------
__global__ __launch_bounds__(256)
void cvt3_bf16(const float* __restrict__ s0, const float* __restrict__ s1,
               const float* __restrict__ s2, unsigned short* __restrict__ out,
               int n8each)
{
  const float* src = (blockIdx.y == 0) ? s0 : (blockIdx.y == 1) ? s1 : s2;
  unsigned short* dst = out + (size_t)blockIdx.y * ((size_t)n8each * 8);
  int i = blockIdx.x * blockDim.x + threadIdx.x;
  const int stride = gridDim.x * blockDim.x;
  for (; i < n8each; i += stride) {
    const float4* p = (const float4*)src + (size_t)i * 2;
    float4 a = p[0], b = p[1];
    ushort8 o;
    o[0] = f2bf(a.x); o[1] = f2bf(a.y); o[2] = f2bf(a.z); o[3] = f2bf(a.w);
    o[4] = f2bf(b.x); o[5] = f2bf(b.y); o[6] = f2bf(b.z); o[7] = f2bf(b.w);
    *((ushort8*)dst + i) = o;
  }
}

// ---------------------------------------------------------------------------
// W_eff[j,d] = sum_h Wl[j, h*1024 + d]  -> bf16 [1024,1024]
// ---------------------------------------------------------------------------
__global__ __launch_bounds__(256)
void weff_kernel(const float* __restrict__ Wl, unsigned short* __restrict__ out)
{
  const int idx = blockIdx.x * 256 + threadIdx.x;   // 0 .. 262143
  const int j = idx >> 8;
  const int d = (idx & 255) << 2;
  float4 s = make_float4(0.f, 0.f, 0.f, 0.f);
  #pragma unroll
  for (int h = 0; h < 8; ++h) {
    float4 w = *(const float4*)&Wl[(size_t)j * 8192 + h * 1024 + d];
    s.x += w.x; s.y += w.y; s.z += w.z; s.w += w.w;
  }
  ushort4v o;
  o[0] = f2bf(s.x); o[1] = f2bf(s.y); o[2] = f2bf(s.z); o[3] = f2bf(s.w);
  *(ushort4v*)&out[(size_t)j * 1024 + d] = o;
}

__global__ __launch_bounds__(256)
void zero_f32(float* __restrict__ p, int n)
{
  const int i = blockIdx.x * 256 + threadIdx.x;
  if (i < n) p[i] = 0.f;
}

// ---------------------------------------------------------------------------
extern "C" void kernel_launch(void* const* d_in, const int* in_sizes, int n_in,
                              void* d_out, int out_size, void* d_ws, size_t ws_size,
                              hipStream_t stream)
{
  (void)in_sizes; (void)n_in; (void)out_size; (void)ws_size;

  const float* Q  = (const float*)d_in[0];
  const float* K  = (const float*)d_in[1];
  const float* V  = (const float*)d_in[2];
  const float* WQ = (const float*)d_in[3];
  const float* bQ = (const float*)d_in[4];
  const float* WK = (const float*)d_in[5];
  const float* bK = (const float*)d_in[6];
  const float* WV = (const float*)d_in[7];
  const float* bV = (const float*)d_in[8];
  const float* Wl = (const float*)d_in[9];
  const float* bl = (const float*)d_in[10];

  const size_t nX = (size_t)8192 * 1024;   // B*S*D
  const size_t nW = (size_t)1024 * 1024;

  // workspace layout (bf16 elements); P overlays Qb+Kb, Z overlays Vb
  unsigned short* Qb  = (unsigned short*)d_ws;   // Qb,Kb,Vb contiguous
  unsigned short* Vb  = Qb + 2 * nX;
  unsigned short* qb  = Vb + nX;                 // qb,kb,vT contiguous
  unsigned short* vT  = qb + 2 * nX;             // [B][D][S]
  unsigned short* Wqb = vT + nX;                 // Wqb,Wkb,Wvb contiguous
  unsigned short* Wef = Wqb + 3 * nW;
  float*          rowsum = (float*)(Wef + nW);   // 8192 f32
  unsigned short* P   = Qb;                      // [B][S][S] = 2*nX
  unsigned short* kb  = qb + nX;
  unsigned short* Zb  = Vb;                      // [B*S][D]

  const int thr = 256;

  cvt3_bf16<<<dim3(1024, 3), thr, 0, stream>>>(Q, K, V, Qb, (int)(nX / 8));
  cvt3_bf16<<<dim3(512, 3),  thr, 0, stream>>>(WQ, WK, WV, Wqb, (int)(nW / 8));
  weff_kernel<<<1024, thr, 0, stream>>>(Wl, Wef);
  zero_f32<<<32, thr, 0, stream>>>(rowsum, 8192);

  // fused projections: z=0 -> qb, z=1 -> kb, z=2 -> vT (transposed)
  gemm_bt<1, 2><<<1536, thr, 0, stream>>>(
      Qb, Wqb, bQ, bK, bV, nullptr, qb, 1024, 1024, 1.f,
      (long)nX, (long)nW, (long)nX, 8, 64);
  // P = exp(q*k^T / 32), rowsum accumulated
  gemm_bt<0, 3><<<1024, thr, 0, stream>>>(
      qb, kb, nullptr, nullptr, nullptr, rowsum, P, 2048, 1024, 0.03125f,
      (long)(2048 * 1024), (long)(2048 * 1024), (long)(2048 * 2048), 16, 16);
  // Z = (P * vT^T) / rowsum
  gemm_bt<0, 4><<<512, thr, 0, stream>>>(
      P, vT, rowsum, nullptr, nullptr, nullptr, Zb, 1024, 2048, 1.f,
      (long)(2048 * 2048), (long)(1024 * 2048), (long)(2048 * 1024), 8, 16);
  // out = Z * Weff^T + bl  -> f32
  gemm_bt<1, 1><<<512, thr, 0, stream>>>(
      Zb, Wef, bl, nullptr, nullptr, nullptr, d_out, 1024, 1024, 1.f,
      0, 0, 0, 8, 64);
}

// Round 4
// 204.424 us; speedup vs baseline: 1.0639x; 1.0639x over previous
//
#include <hip/hip_runtime.h>
#include <stdint.h>

#define DEV __device__ __forceinline__

typedef __attribute__((ext_vector_type(8))) unsigned short frag8;    // 8 bf16 = 4 VGPR
typedef __attribute__((ext_vector_type(4))) float f32x4;
typedef __attribute__((ext_vector_type(8))) unsigned short ushort8;
typedef __attribute__((ext_vector_type(4))) unsigned short ushort4v;

DEV unsigned short f2bf(float f) {
  union { float f; unsigned u; } x; x.f = f;
  unsigned r = x.u + 0x7fffu + ((x.u >> 16) & 1u);   // RNE
  return (unsigned short)(r >> 16);
}
DEV float bf2f(unsigned short b) {
  union { unsigned u; float f; } x; x.u = ((unsigned)b) << 16;
  return x.f;
}

DEV void gload_lds16(const void* g, void* l) {
  __builtin_amdgcn_global_load_lds((const __attribute__((address_space(1))) void*)g,
                                   (__attribute__((address_space(3))) void*)l, 16, 0, 0);
}

DEV void mfma_bf16(f32x4& c, frag8 a, frag8 b) {
  asm("v_mfma_f32_16x16x32_bf16 %0, %1, %2, %0" : "+v"(c) : "v"(a), "v"(b));
}

DEV void wait_vm8_barrier() {
  asm volatile("s_waitcnt vmcnt(8)" ::: "memory");
  __builtin_amdgcn_s_barrier();
  __builtin_amdgcn_sched_barrier(0);
}
DEV void wait_vm0_barrier() {
  asm volatile("s_waitcnt vmcnt(0)" ::: "memory");
  __builtin_amdgcn_s_barrier();
  __builtin_amdgcn_sched_barrier(0);
}
DEV void raw_barrier() {
  __builtin_amdgcn_s_barrier();
  __builtin_amdgcn_sched_barrier(0);
}

// ---------------------------------------------------------------------------
// C[M,N] = A[M,K]*B[N,K]^T, bf16 in / f32 acc. 128x128 tile, BK=64, 4 waves,
// double-buffered LDS, counted-vmcnt 2-phase prefetch. XOR-swizzled LDS via
// pre-swizzled global source. 1D grid + bijective XCD swizzle.
// MODE: 0 = bf16 out
//       3 = scores: e = exp((s + c2[bz*N+gc])*scale), bf16 out, rowsum atomics
//       4 = PV: f32 out = acc/rowsum[row] + biasp[gc]
//       5 = fused q'/v': bz==0 plain bf16; bz==1 per-batch transposed store
// ---------------------------------------------------------------------------
template<int MODE>
__global__ __launch_bounds__(256)
void gemm_bt(const unsigned short* __restrict__ A,
             const unsigned short* __restrict__ Bm,
             const float* __restrict__ bias0, const float* __restrict__ bias1,
             float* __restrict__ rowsum,
             void* __restrict__ Cv,
             int N, int K, float scale,
             long sA, long sB, long sC,
             int nx, int ny)
{
  __shared__ unsigned short lds[2][2][128 * 64];   // [buf][A/B], 64 KiB

  const int tid  = threadIdx.x;
  const int lane = tid & 63;
  const int wave = tid >> 6;
  const int wm   = wave >> 1;           // 2x2 waves, 64x64 each
  const int wn   = wave & 1;

  // ---- bijective XCD swizzle (m204) + grid decomposition ----
  const unsigned nwg = gridDim.x;
  const unsigned orig = blockIdx.x;
  const unsigned qq = nwg >> 3, rr = nwg & 7;
  const unsigned xcd = orig & 7, jj = orig >> 3;
  const unsigned wg = (xcd < rr ? xcd * (qq + 1) : rr * (qq + 1) + (xcd - rr) * qq) + jj;
  const unsigned bx = wg % (unsigned)nx;
  const unsigned tt = wg / (unsigned)nx;
  const unsigned by = tt % (unsigned)ny;
  const unsigned bz = tt / (unsigned)ny;

  const int bm = (int)by * 128;
  const int bn = (int)bx * 128;

  A  += (size_t)bz * (size_t)sA;
  Bm += (size_t)bz * (size_t)sB;

  // ---- staging addresses ----
  const int r8  = lane >> 3;
  const int l8  = lane & 7;
  const int swz = ((l8 ^ r8) << 4);     // pre-swizzled global byte column
  const size_t Kb = (size_t)K * 2;

  const char* gA = (const char*)A  + (size_t)(bm + wave * 32 + r8) * Kb + swz;
  const char* gB = (const char*)Bm + (size_t)(bn + wave * 32 + r8) * Kb + swz;
  char* lA0 = (char*)&lds[0][0][0] + wave * 32 * 128;
  char* lB0 = (char*)&lds[0][1][0] + wave * 32 * 128;
  char* lA1 = (char*)&lds[1][0][0] + wave * 32 * 128;
  char* lB1 = (char*)&lds[1][1][0] + wave * 32 * 128;

  // ---- fragment read addresses ----
  const int cr = lane & 15;
  const int kq = lane >> 4;
  const int base16 = ((kq ^ (cr & 7)) << 4);
  const char* rA0 = (const char*)&lds[0][0][0] + (wm * 64 + cr) * 128;
  const char* rB0 = (const char*)&lds[0][1][0] + (wn * 64 + cr) * 128;
  const char* rA1 = (const char*)&lds[1][0][0] + (wm * 64 + cr) * 128;
  const char* rB1 = (const char*)&lds[1][1][0] + (wn * 64 + cr) * 128;

  f32x4 acc[4][4];
  #pragma unroll
  for (int m = 0; m < 4; ++m)
    #pragma unroll
    for (int n = 0; n < 4; ++n)
      acc[m][n] = f32x4{0.f, 0.f, 0.f, 0.f};

  auto STAGE = [&](int t, char* la, char* lb) {
    const char* ga = gA + (size_t)t * 128;
    const char* gb = gB + (size_t)t * 128;
    gload_lds16(ga,               la);
    gload_lds16(gb,               lb);
    gload_lds16(ga +  8 * Kb,     la + 1024);
    gload_lds16(gb +  8 * Kb,     lb + 1024);
    gload_lds16(ga + 16 * Kb,     la + 2048);
    gload_lds16(gb + 16 * Kb,     lb + 2048);
    gload_lds16(ga + 24 * Kb,     la + 3072);
    gload_lds16(gb + 24 * Kb,     lb + 3072);
  };
  auto COMPUTE = [&](const char* ra, const char* rb) {
    #pragma unroll
    for (int kk = 0; kk < 2; ++kk) {
      const int off = base16 ^ (kk << 6);
      frag8 a[4], b[4];
      #pragma unroll
      for (int f = 0; f < 4; ++f) {
        a[f] = *(const frag8*)(ra + f * 2048 + off);
        b[f] = *(const frag8*)(rb + f * 2048 + off);
      }
      #pragma unroll
      for (int m = 0; m < 4; ++m)
        #pragma unroll
        for (int n = 0; n < 4; ++n)
          mfma_bf16(acc[m][n], a[m], b[n]);
    }
  };

  const int nk = K >> 6;
  STAGE(0, lA0, lB0);
  for (int t = 0; t < nk; ++t) {
    const bool odd = t & 1;
    if (t + 1 < nk) {
      STAGE(t + 1, odd ? lA0 : lA1, odd ? lB0 : lB1);
      wait_vm8_barrier();
    } else {
      wait_vm0_barrier();
    }
    COMPUTE(odd ? rA1 : rA0, odd ? rB1 : rB0);
    raw_barrier();
  }

  // ---- epilogue: C/D layout col=lane&15, row=(lane>>4)*4+i (m89-verified) --
  #pragma unroll
  for (int m = 0; m < 4; ++m) {
    const int gr0 = bm + wm * 64 + m * 16 + kq * 4;
    float psum[4] = {0.f, 0.f, 0.f, 0.f};       // MODE 3 row partials
    float inv0 = 1.f, inv1 = 1.f, inv2 = 1.f, inv3 = 1.f;
    if constexpr (MODE == 4) {
      const float4 rs = *(const float4*)&bias0[(size_t)bz * 2048 + gr0];
      inv0 = 1.f / rs.x; inv1 = 1.f / rs.y; inv2 = 1.f / rs.z; inv3 = 1.f / rs.w;
    }
    #pragma unroll
    for (int n = 0; n < 4; ++n) {
      const int gc = bn + wn * 64 + n * 16 + cr;
      float v0 = acc[m][n][0], v1 = acc[m][n][1], v2 = acc[m][n][2], v3 = acc[m][n][3];
      if constexpr (MODE == 3) {
        const float c2v = bias0[(size_t)bz * (size_t)N + gc];
        unsigned short* C = (unsigned short*)Cv + (size_t)bz * (size_t)sC;
        unsigned short e0 = f2bf(__expf((v0 + c2v) * scale));
        unsigned short e1 = f2bf(__expf((v1 + c2v) * scale));
        unsigned short e2 = f2bf(__expf((v2 + c2v) * scale));
        unsigned short e3 = f2bf(__expf((v3 + c2v) * scale));
        C[(size_t)(gr0 + 0) * N + gc] = e0;
        C[(size_t)(gr0 + 1) * N + gc] = e1;
        C[(size_t)(gr0 + 2) * N + gc] = e2;
        C[(size_t)(gr0 + 3) * N + gc] = e3;
        psum[0] += bf2f(e0); psum[1] += bf2f(e1);
        psum[2] += bf2f(e2); psum[3] += bf2f(e3);
      } else if constexpr (MODE == 4) {
        const float bb = bias1[gc];
        float* C = (float*)Cv + (size_t)bz * (size_t)sC;
        C[(size_t)(gr0 + 0) * N + gc] = v0 * inv0 + bb;
        C[(size_t)(gr0 + 1) * N + gc] = v1 * inv1 + bb;
        C[(size_t)(gr0 + 2) * N + gc] = v2 * inv2 + bb;
        C[(size_t)(gr0 + 3) * N + gc] = v3 * inv3 + bb;
      } else if constexpr (MODE == 5) {
        if (bz == 1) {
          // transposed store: v'T[b][d][s], b = gr0>>11, s = gr0&2047, d = gc
          unsigned short* C = (unsigned short*)Cv + (size_t)sC;
          ushort4v u;
          u[0] = f2bf(v0); u[1] = f2bf(v1); u[2] = f2bf(v2); u[3] = f2bf(v3);
          *(ushort4v*)&C[((size_t)(gr0 >> 11) << 21) + (size_t)gc * 2048 + (gr0 & 2047)] = u;
        } else {
          unsigned short* C = (unsigned short*)Cv;
          C[(size_t)(gr0 + 0) * N + gc] = f2bf(v0);
          C[(size_t)(gr0 + 1) * N + gc] = f2bf(v1);
          C[(size_t)(gr0 + 2) * N + gc] = f2bf(v2);
          C[(size_t)(gr0 + 3) * N + gc] = f2bf(v3);
        }
      } else {
        unsigned short* C = (unsigned short*)Cv + (size_t)bz * (size_t)sC;
        C[(size_t)(gr0 + 0) * N + gc] = f2bf(v0);
        C[(size_t)(gr0 + 1) * N + gc] = f2bf(v1);
        C[(size_t)(gr0 + 2) * N + gc] = f2bf(v2);
        C[(size_t)(gr0 + 3) * N + gc] = f2bf(v3);
      }
    }
    if constexpr (MODE == 3) {
      #pragma unroll
      for (int j = 0; j < 4; ++j) {
        float p = psum[j];
        p += __shfl_xor(p, 1);
        p += __shfl_xor(p, 2);
        p += __shfl_xor(p, 4);
        p += __shfl_xor(p, 8);
        if (cr == 0) atomicAdd(&rowsum[(size_t)bz * 2048 + gr0 + j], p);
      }
    }
  }
}

// ---------------------------------------------------------------------------
// fused f32 -> bf16 for three equal-size tensors (blockIdx.y selects)
// ---------------------------------------------------------------------------
__global__ __launch_bounds__(256)
void cvt3_bf16(const float* __restrict__ s0, const float* __restrict__ s1,
               const float* __restrict__ s2, unsigned short* __restrict__ out,
               int n8each)
{
  const float* src = (blockIdx.y == 0) ? s0 : (blockIdx.y == 1) ? s1 : s2;
  unsigned short* dst = out + (size_t)blockIdx.y * ((size_t)n8each * 8);
  int i = blockIdx.x * blockDim.x + threadIdx.x;
  const int stride = gridDim.x * blockDim.x;
  for (; i < n8each; i += stride) {
    const float4* p = (const float4*)src + (size_t)i * 2;
    float4 a = p[0], b = p[1];
    ushort8 o;
    o[0] = f2bf(a.x); o[1] = f2bf(a.y); o[2] = f2bf(a.z); o[3] = f2bf(a.w);
    o[4] = f2bf(b.x); o[5] = f2bf(b.y); o[6] = f2bf(b.z); o[7] = f2bf(b.w);
    *((ushort8*)dst + i) = o;
  }
}

// ---------------------------------------------------------------------------
// transpose-convert three 1024x1024 f32 -> bf16: dst[a][b] = src[b][a]
// dst slots in weight region: z=0(WQ)->+2nW, z=1(WK)->+0, z=2(WV)->+3nW
// ---------------------------------------------------------------------------
__global__ __launch_bounds__(256)
void tpose3(const float* __restrict__ s0, const float* __restrict__ s1,
            const float* __restrict__ s2, unsigned short* __restrict__ wr)
{
  const int z = blockIdx.y;
  const float* src = (z == 0) ? s0 : (z == 1) ? s1 : s2;
  unsigned short* dst = wr + (size_t)((z == 0) ? 2 : (z == 1) ? 0 : 3) * 1024 * 1024;

  __shared__ float t[64][65];
  const int bx  = blockIdx.x & 15;      // col tile of src
  const int byy = blockIdx.x >> 4;      // row tile of src
  const int tx  = threadIdx.x & 63;
  const int ty4 = threadIdx.x >> 6;     // 0..3

  #pragma unroll
  for (int i = 0; i < 16; ++i) {
    const int r = i * 4 + ty4;
    t[r][tx] = src[(size_t)(byy * 64 + r) * 1024 + bx * 64 + tx];
  }
  __syncthreads();
  #pragma unroll
  for (int i = 0; i < 16; ++i) {
    const int r = i * 4 + ty4;
    dst[(size_t)(bx * 64 + r) * 1024 + byy * 64 + tx] = f2bf(t[tx][r]);
  }
}

// ---------------------------------------------------------------------------
// W_eff[j,d] = sum_h Wl[j, h*1024 + d]  -> bf16 [1024,1024]
// ---------------------------------------------------------------------------
__global__ __launch_bounds__(256)
void weff_kernel(const float* __restrict__ Wl, unsigned short* __restrict__ out)
{
  const int idx = blockIdx.x * 256 + threadIdx.x;   // 0 .. 262143
  const int j = idx >> 8;
  const int d = (idx & 255) << 2;
  float4 s = make_float4(0.f, 0.f, 0.f, 0.f);
  #pragma unroll
  for (int h = 0; h < 8; ++h) {
    float4 w = *(const float4*)&Wl[(size_t)j * 8192 + h * 1024 + d];
    s.x += w.x; s.y += w.y; s.z += w.z; s.w += w.w;
  }
  ushort4v o;
  o[0] = f2bf(s.x); o[1] = f2bf(s.y); o[2] = f2bf(s.z); o[3] = f2bf(s.w);
  *(ushort4v*)&out[(size_t)j * 1024 + d] = o;
}

__global__ __launch_bounds__(256)
void zero_f32(float* __restrict__ p, int n)
{
  const int i = blockIdx.x * 256 + threadIdx.x;
  if (i < n) p[i] = 0.f;
}

// u2[k] += sum_{m in chunk} WK[m,k] * bQ[m]   (grid.x: k-chunks, grid.y: m-chunks)
__global__ __launch_bounds__(256)
void u2_kernel(const float* __restrict__ WK, const float* __restrict__ bQ,
               float* __restrict__ u2)
{
  const int k = blockIdx.x * 256 + threadIdx.x;
  const int m0 = blockIdx.y * 256;
  float a = 0.f;
  for (int m = m0; m < m0 + 256; ++m)
    a += WK[(size_t)m * 1024 + k] * bQ[m];
  atomicAdd(&u2[k], a);
}

// c2[r] = Kb[r,:] . u2   (wave per row, bf16 K)
__global__ __launch_bounds__(256)
void c2_kernel(const unsigned short* __restrict__ Kb, const float* __restrict__ u2,
               float* __restrict__ c2)
{
  const int lane = threadIdx.x & 63;
  const int w    = threadIdx.x >> 6;
  const int r    = blockIdx.x * 4 + w;
  const unsigned short* kr = Kb + (size_t)r * 1024 + lane * 16;
  ushort8 a = *(const ushort8*)kr;
  ushort8 b = *(const ushort8*)(kr + 8);
  const float* uu = u2 + lane * 16;
  float s = 0.f;
  #pragma unroll
  for (int i = 0; i < 8; ++i) s += bf2f(a[i]) * uu[i];
  #pragma unroll
  for (int i = 0; i < 8; ++i) s += bf2f(b[i]) * uu[8 + i];
  #pragma unroll
  for (int off = 32; off; off >>= 1) s += __shfl_xor(s, off);
  if (lane == 0) c2[r] = s;
}

// biasp[j] = Weffb[j,:] . bV + bl[j]   (wave per row)
__global__ __launch_bounds__(256)
void biasp_kernel(const unsigned short* __restrict__ Weffb, const float* __restrict__ bV,
                  const float* __restrict__ bl, float* __restrict__ biasp)
{
  const int lane = threadIdx.x & 63;
  const int w    = threadIdx.x >> 6;
  const int j    = blockIdx.x * 4 + w;
  const unsigned short* wr = Weffb + (size_t)j * 1024 + lane * 16;
  ushort8 a = *(const ushort8*)wr;
  ushort8 b = *(const ushort8*)(wr + 8);
  const float* vv = bV + lane * 16;
  float s = 0.f;
  #pragma unroll
  for (int i = 0; i < 8; ++i) s += bf2f(a[i]) * vv[i];
  #pragma unroll
  for (int i = 0; i < 8; ++i) s += bf2f(b[i]) * vv[8 + i];
  #pragma unroll
  for (int off = 32; off; off >>= 1) s += __shfl_xor(s, off);
  if (lane == 0) biasp[j] = s + bl[j];
}

// ---------------------------------------------------------------------------
extern "C" void kernel_launch(void* const* d_in, const int* in_sizes, int n_in,
                              void* d_out, int out_size, void* d_ws, size_t ws_size,
                              hipStream_t stream)
{
  (void)in_sizes; (void)n_in; (void)out_size; (void)ws_size;

  const float* Q  = (const float*)d_in[0];
  const float* K  = (const float*)d_in[1];
  const float* V  = (const float*)d_in[2];
  const float* WQ = (const float*)d_in[3];
  const float* bQ = (const float*)d_in[4];
  const float* WK = (const float*)d_in[5];
  const float* bK = (const float*)d_in[6];  (void)bK;  // cancels in softmax
  const float* WV = (const float*)d_in[7];
  const float* bV = (const float*)d_in[8];
  const float* Wl = (const float*)d_in[9];
  const float* bl = (const float*)d_in[10];

  const size_t nX = (size_t)8192 * 1024;   // B*S*D
  const size_t nW = (size_t)1024 * 1024;

  // workspace (bf16 elements):
  // [Qb][Vb][Kb][q'][v'T] | weights: [WKt][Weffb][WQt][WVt][Tt][Wve] | f32 vecs
  unsigned short* Qb  = (unsigned short*)d_ws;
  unsigned short* Vb  = Qb + nX;
  unsigned short* Kb  = Qb + 2 * nX;
  unsigned short* qp  = Qb + 3 * nX;       // q' [8192][1024]
  unsigned short* vpT = Qb + 4 * nX;       // v'T [4][1024][2048]
  unsigned short* Wr  = Qb + 5 * nX;       // weight region base (= WKt)
  unsigned short* Weffb = Wr + nW;
  unsigned short* WQt   = Wr + 2 * nW;
  unsigned short* Tt    = Wr + 4 * nW;
  float* Fv   = (float*)(Wr + 6 * nW);
  float* rowsum = Fv;                      // 8192
  float* u2     = Fv + 8192;               // 1024
  float* c2     = Fv + 9216;               // 8192
  float* biasp  = Fv + 17408;              // 1024
  unsigned short* P = Qb;                  // [4][2048][2048] overlays Qb+Vb

  const int thr = 256;

  cvt3_bf16<<<dim3(1024, 3), thr, 0, stream>>>(Q, V, K, Qb, (int)(nX / 8));
  tpose3<<<dim3(256, 3), thr, 0, stream>>>(WQ, WK, WV, Wr);
  weff_kernel<<<1024, thr, 0, stream>>>(Wl, Weffb);
  zero_f32<<<36, thr, 0, stream>>>(rowsum, 9216);          // rowsum + u2
  u2_kernel<<<dim3(4, 4), thr, 0, stream>>>(WK, bQ, u2);
  biasp_kernel<<<256, thr, 0, stream>>>(Weffb, bV, bl, biasp);
  c2_kernel<<<2048, thr, 0, stream>>>(Kb, u2, c2);

  // Tt = WK^T @ WQ (= (WQ^T WK)^T), Wve = Weff @ WV   (fused via z)
  gemm_bt<0><<<128, thr, 0, stream>>>(
      Wr, WQt, nullptr, nullptr, nullptr, Tt, 1024, 1024, 1.f,
      (long)nW, (long)nW, (long)nW, 8, 8);
  // q' = Qb @ Tt^T (z=0), v'T = (Vb @ Wve^T)^T per batch (z=1)
  gemm_bt<5><<<1024, thr, 0, stream>>>(
      Qb, Tt, nullptr, nullptr, nullptr, qp, 1024, 1024, 1.f,
      (long)nX, (long)nW, (long)nX, 8, 64);
  // P = exp((q' K^T + c2)/32), rowsum accumulated
  gemm_bt<3><<<1024, thr, 0, stream>>>(
      qp, Kb, c2, nullptr, rowsum, P, 2048, 1024, 0.03125f,
      (long)(2048 * 1024), (long)(2048 * 1024), (long)(2048 * 2048), 16, 16);
  // out = (P @ v'T^T)/rowsum + biasp   -> f32
  gemm_bt<4><<<512, thr, 0, stream>>>(
      P, vpT, rowsum, biasp, nullptr, d_out, 1024, 2048, 1.f,
      (long)(2048 * 2048), (long)(1024 * 2048), (long)(2048 * 1024), 8, 16);
}